// Round 9
// baseline (239.697 us; speedup 1.0000x reference)
//
#include <hip/hip_runtime.h>
#include <hip/hip_bf16.h>

// Problem: B=8, T=4096, D=64, K=1024. N = B*T = 32768 rows.
// Inputs:  d_in[0] = x (f32, 2097152), d_in[1] = embeddings (f32, [D][K] = 64x1024)
// Output: FLOAT32, concatenated in return order:
//   quantized (2097152) | encodings (33554432) | indices (32768) | loss (1)

#define NROWS 32768
#define DDIM  64
#define KCB   1024
#define NSEG  8
#define SEG   128        // codes per K-segment

typedef float f32x4 __attribute__((ext_vector_type(4)));

// ws layout (float index):
#define WS_ET    0        // Et [K][D] transposed embeddings (65536 f32)
#define WS_H     65536    // 0.5*||e_k||^2 (1024)
#define WS_PART  66560    // per-block loss partials (2048 f32)
#define WS_PBEST 68608    // per-(seg,row) best score (8*32768 f32)
#define WS_PIDX  330752   // per-(seg,row) best index (8*32768 u16 = 131072 f32)
// end: 461824 f32 = 1.85 MB

// K1: transpose E (D,K) -> Et (K,D), h[k] = 0.5*||e_k||^2.
__global__ __launch_bounds__(256) void k1_prep(const float* __restrict__ E,
                                               float* __restrict__ Et,
                                               float* __restrict__ h) {
  int k = blockIdx.x * 256 + threadIdx.x;   // 0..1023
  float col[DDIM];
  float sum = 0.f;
#pragma unroll
  for (int d = 0; d < DDIM; ++d) {
    float v = E[d * KCB + k];               // coalesced across lanes
    col[d] = v;
    sum = fmaf(v, v, sum);
  }
  float4* dst = (float4*)(Et + (size_t)k * DDIM);
#pragma unroll
  for (int i = 0; i < 16; ++i)
    dst[i] = make_float4(col[4*i], col[4*i+1], col[4*i+2], col[4*i+3]);
  h[k] = 0.5f * sum;
}

// K2: register-tiled GEMM-argmax. Block = 64 rows x 128 codes (one segment).
// Thread (r = tid>>4, c = tid&15) computes rows {r+16m} x codes {c+16j},
// a 4x8 f32 accumulator tile. Both operands staged in LDS with +4-float pad
// (stride 17 float4): every ds_read_b128 feeds ~10.7 FMAs, <=2-way banks.
// No long-lived x registers -> nothing for the rematerializer to sink.
__global__ __launch_bounds__(256, 3) void k2_score(const float* __restrict__ x,
                                                   const float* __restrict__ Et,
                                                   const float* __restrict__ h,
                                                   float* __restrict__ pbest,
                                                   unsigned short* __restrict__ pidx) {
  __shared__ float sx[64 * 68];      // x-tile  [row][68]  (17408 B)
  __shared__ float se_[128 * 68];    // e-tile  [code][68] (34816 B)
  __shared__ float sh[SEG];          // 0.5*||e||^2        (512 B)

  int bid = blockIdx.x;              // 0..4095
  int ks  = bid >> 9;                // segment 0..7 (512 consecutive blocks share seg)
  int rt  = bid & 511;               // row-tile 0..511
  int tid = threadIdx.x;
  int c   = tid & 15;                // code-group
  int r   = tid >> 4;                // row-group

  // stage x-tile: 1024 float4, 4 per thread, coalesced global reads
  {
    const float4* src = (const float4*)(x + (size_t)rt * 64 * DDIM);
    float4* dst = (float4*)sx;
#pragma unroll
    for (int i = 0; i < 4; ++i) {
      int f = tid + i * 256;
      dst[(f >> 4) * 17 + (f & 15)] = src[f];
    }
  }
  // stage e-tile: 2048 float4, 8 per thread
  {
    const float4* src = (const float4*)(Et + (size_t)ks * SEG * DDIM);
    float4* dst = (float4*)se_;
#pragma unroll
    for (int i = 0; i < 8; ++i) {
      int f = tid + i * 256;
      dst[(f >> 4) * 17 + (f & 15)] = src[f];
    }
  }
  if (tid < SEG) sh[tid] = h[ks * SEG + tid];
  __syncthreads();

  float acc[4][8];
#pragma unroll
  for (int m = 0; m < 4; ++m)
#pragma unroll
    for (int j = 0; j < 8; ++j) acc[m][j] = -sh[c + 16 * j];

  const float4* sxf = (const float4*)sx;
  const float4* sef = (const float4*)se_;

#pragma unroll 2
  for (int kk = 0; kk < 16; ++kk) {
    float4 xv[4], ev[8];
#pragma unroll
    for (int m = 0; m < 4; ++m) xv[m] = sxf[(r + 16 * m) * 17 + kk];
#pragma unroll
    for (int j = 0; j < 8; ++j) ev[j] = sef[(c + 16 * j) * 17 + kk];
#pragma unroll
    for (int m = 0; m < 4; ++m) {
#pragma unroll
      for (int j = 0; j < 8; ++j) {
        float a = acc[m][j];
        a = fmaf(xv[m].x, ev[j].x, a);
        a = fmaf(xv[m].y, ev[j].y, a);
        a = fmaf(xv[m].z, ev[j].z, a);
        a = fmaf(xv[m].w, ev[j].w, a);
        acc[m][j] = a;
      }
    }
  }
  __syncthreads();                     // e-tile reads done; reuse se_ for reduction

  float* sbest = se_;                  // [64][17] padded
  int*   sidxv = (int*)(se_ + 64 * 17);

#pragma unroll
  for (int m = 0; m < 4; ++m) {
    float bm = acc[m][0];
    int   im = c;                      // code offset within segment (j=0)
#pragma unroll
    for (int j = 1; j < 8; ++j) {
      int code = c + 16 * j;
      if (acc[m][j] > bm || (acc[m][j] == bm && code < im)) { bm = acc[m][j]; im = code; }
    }
    int row = r + 16 * m;
    sbest[row * 17 + c] = bm;
    sidxv[row * 17 + c] = im;
  }
  __syncthreads();

  if (tid < 64) {
    int row = tid;
    float b = sbest[row * 17];
    int  ic = sidxv[row * 17];
#pragma unroll
    for (int cc = 1; cc < 16; ++cc) {
      float b2 = sbest[row * 17 + cc];
      int   i2 = sidxv[row * 17 + cc];
      if (b2 > b || (b2 == b && i2 < ic)) { b = b2; ic = i2; }
    }
    int n = rt * 64 + row;
    pbest[ks * NROWS + n] = b;
    pidx [ks * NROWS + n] = (unsigned short)(ks * SEG + ic);
  }
}

// K34 fused: combine segments -> index (16 rows/block); indices, quantized
// (1 float4/thread, coalesced), loss partial (plain store), one-hot stream.
__global__ __launch_bounds__(256) void k34_fused(const float* __restrict__ x,
                                                 const float* __restrict__ Et,
                                                 const float* __restrict__ pbest,
                                                 const unsigned short* __restrict__ pidx,
                                                 float* __restrict__ partial,
                                                 float* __restrict__ out_q,
                                                 float* __restrict__ out_enc,
                                                 float* __restrict__ out_ind) {
  __shared__ int sidx[16];
  int tid = threadIdx.x;
  int r0 = blockIdx.x * 16;

  if (tid < 16) {
    int n = r0 + tid;
    float best = pbest[n];
    int bi = pidx[n];
#pragma unroll
    for (int q = 1; q < NSEG; ++q) {          // ascending segs + lex tie-break
      float b = pbest[q * NROWS + n];
      int i2 = (int)pidx[q * NROWS + n];
      if (b > best || (b == best && i2 < bi)) { best = b; bi = i2; }
    }
    sidx[tid] = bi;
    out_ind[n] = (float)bi;
  }
  __syncthreads();

  // quantized gather + loss: thread covers row r0+(tid>>4), dims [4*(tid&15), +4)
  int r = tid >> 4, cc = tid & 15;
  int n = r0 + r;
  int bi = sidx[r];
  float4 q4 = *(const float4*)(Et + (size_t)bi * DDIM + cc * 4);  // L2-resident gather
  float4 x4 = *(const float4*)(x + (size_t)n * DDIM + cc * 4);    // coalesced
  float d0 = q4.x - x4.x, d1 = q4.y - x4.y, d2 = q4.z - x4.z, d3 = q4.w - x4.w;
  float lsum = 0.f;
  lsum = fmaf(d0, d0, lsum); lsum = fmaf(d1, d1, lsum);
  lsum = fmaf(d2, d2, lsum); lsum = fmaf(d3, d3, lsum);
  *(float4*)(out_q + (size_t)n * DDIM + cc * 4) = q4;

  // one-hot encodings: thread t covers cols [4t, 4t+4) of each of 16 rows
#pragma unroll
  for (int rr = 0; rr < 16; ++rr) {
    int bk = sidx[rr];
    f32x4 v = (f32x4)(0.f);
    if ((bk >> 2) == tid) v[bk & 3] = 1.0f;
    __builtin_nontemporal_store(v, (f32x4*)(out_enc + (size_t)(r0 + rr) * KCB + tid * 4));
  }

  // block loss reduction -> plain store
#pragma unroll
  for (int off = 32; off > 0; off >>= 1) lsum += __shfl_down(lsum, off);
  __shared__ float red[4];
  int lane = tid & 63, w = tid >> 6;
  if (lane == 0) red[w] = lsum;
  __syncthreads();
  if (tid == 0) partial[blockIdx.x] = red[0] + red[1] + red[2] + red[3];
}

// K5: reduce 2048 partials -> loss.
__global__ void k5_loss(const float* __restrict__ partial, float* __restrict__ out_loss) {
  int t = threadIdx.x;                 // 256 threads
  float s = 0.f;
#pragma unroll
  for (int i = 0; i < 8; ++i) s += partial[t + i * 256];
#pragma unroll
  for (int off = 32; off > 0; off >>= 1) s += __shfl_down(s, off);
  __shared__ float red[4];
  int lane = t & 63, w = t >> 6;
  if (lane == 0) red[w] = s;
  __syncthreads();
  if (t == 0) out_loss[0] = (red[0] + red[1] + red[2] + red[3]) * (1.0f / 2097152.0f);
}

extern "C" void kernel_launch(void* const* d_in, const int* in_sizes, int n_in,
                              void* d_out, int out_size, void* d_ws, size_t ws_size,
                              hipStream_t stream) {
  const float* x = (const float*)d_in[0];
  const float* E = (const float*)d_in[1];

  float* ws    = (float*)d_ws;
  float* Et    = ws + WS_ET;
  float* h     = ws + WS_H;
  float* part  = ws + WS_PART;
  float* pbest = ws + WS_PBEST;
  unsigned short* pidx = (unsigned short*)(ws + WS_PIDX);

  float* out      = (float*)d_out;
  float* out_q    = out;                      // 2097152
  float* out_enc  = out + 2097152;            // 33554432
  float* out_ind  = out + 35651584;           // 32768
  float* out_loss = out + 35684352;           // 1

  k1_prep<<<4, 256, 0, stream>>>(E, Et, h);
  k2_score<<<4096, 256, 0, stream>>>(x, Et, h, pbest, pidx);
  k34_fused<<<2048, 256, 0, stream>>>(x, Et, pbest, pidx, part, out_q, out_enc, out_ind);
  k5_loss<<<1, 256, 0, stream>>>(part, out_loss);
}